// Round 7
// baseline (242.391 us; speedup 1.0000x reference)
//
#include <hip/hip_runtime.h>
#include <cstdint>
#include <cstddef>

#define NEXPERT 32
#define KIN 256
#define NOUT 256
#define NTOK 524288
#define BM 64
#define TPB 16   // tiles per block; grid = NTOK/(BM*TPB) = 512 = 2 blocks/CU

typedef float f32x4 __attribute__((ext_vector_type(4)));
typedef __bf16 bf16x8 __attribute__((ext_vector_type(8)));
typedef unsigned short u16;
typedef u16 u16x8 __attribute__((ext_vector_type(8)));
typedef unsigned int u32;

union BF8 { u16x8 u; bf16x8 b; };

__device__ __forceinline__ u16 f2bf(float f) {
  unsigned u = __float_as_uint(f);
  return (u16)((u + 0x7FFFu + ((u >> 16) & 1u)) >> 16);  // RNE
}

#define GLDS(gp, lp) __builtin_amdgcn_global_load_lds(                      \
    (const __attribute__((address_space(1))) u32*)(gp),                      \
    (__attribute__((address_space(3))) u32*)(u32)(uintptr_t)(lp), 16, 0, 0)

#define VMW(n) asm volatile("s_waitcnt vmcnt(" n ")" ::: "memory")
#define BAR()  do { __builtin_amdgcn_sched_barrier(0);                       \
                    __builtin_amdgcn_s_barrier();                            \
                    __builtin_amdgcn_sched_barrier(0); } while (0)

// ---- prologue: pack W fp32 -> bf16 in MFMA-fragment order ----
// 16B unit t = ((e*8 + kc)*16 + n16)*64 + lane;
// lane holds W[e][n16*16 + (lane&15)][kc*32 + (lane>>4)*8 + j], j=0..7.
__global__ void pack_w_kernel(const float* __restrict__ w, u16* __restrict__ wb) {
  const int t    = blockIdx.x * 256 + threadIdx.x;   // 0..262143
  const int lane = t & 63;
  const int n16  = (t >> 6) & 15;
  const int kc   = (t >> 10) & 7;
  const int e    = t >> 13;
  const float* src = w + (size_t)e * 65536 + (size_t)(n16 * 16 + (lane & 15)) * 256
                       + kc * 32 + (lane >> 4) * 8;
  const float4 a = *reinterpret_cast<const float4*>(src);
  const float4 b = *reinterpret_cast<const float4*>(src + 4);
  u16x8 h;
  h[0]=f2bf(a.x); h[1]=f2bf(a.y); h[2]=f2bf(a.z); h[3]=f2bf(a.w);
  h[4]=f2bf(b.x); h[5]=f2bf(b.y); h[6]=f2bf(b.z); h[7]=f2bf(b.w);
  *reinterpret_cast<u16x8*>(wb + (size_t)t * 8) = h;
}

// ---- load one expert's per-wave B slice into registers (32x16B coalesced) ----
template<bool WSBF>
__device__ __forceinline__ void loadBexp(const u16* __restrict__ wpk, const float* w32,
                                         int e, int wv, int l15, int lg, int lane,
                                         BF8 (&B)[4][2][4]) {
  if (WSBF) {
    const u16* wEL = wpk + ((size_t)e << 16) + (lane << 3);
#pragma unroll
    for (int s = 0; s < 4; ++s)
#pragma unroll
      for (int c = 0; c < 2; ++c)
#pragma unroll
        for (int n = 0; n < 4; ++n)
          B[s][c][n].u = *reinterpret_cast<const u16x8*>(
              wEL + (size_t)((2 * s + c) * 16 + (wv << 2) + n) * 512);
  } else {
#pragma unroll
    for (int s = 0; s < 4; ++s)
#pragma unroll
      for (int c = 0; c < 2; ++c)
#pragma unroll
        for (int n = 0; n < 4; ++n) {
          const float4* p = reinterpret_cast<const float4*>(
              w32 + ((size_t)e << 16) +
              (size_t)((wv << 6) + (n << 4) + l15) * KIN + (2 * s + c) * 32 + lg * 8);
          const float4 x = p[0], y = p[1];
          u16x8 h;
          h[0]=f2bf(x.x); h[1]=f2bf(x.y); h[2]=f2bf(x.z); h[3]=f2bf(x.w);
          h[4]=f2bf(y.x); h[5]=f2bf(y.y); h[6]=f2bf(y.z); h[7]=f2bf(y.w);
          B[s][c][n].u = h;
        }
  }
}

// ---- one K-step of MFMA from staged fp32 LDS buffer (swizzled read) ----
__device__ __forceinline__ void computeStep(const char* sAc, int buf, int l15, int lg,
                                            const BF8 (&bfr)[2][4], f32x4 (&acc)[4][4]) {
  const char* abase = sAc + buf * 16384 + l15 * 256;
#pragma unroll
  for (int c = 0; c < 2; ++c) {
    BF8 af[4];
#pragma unroll
    for (int m = 0; m < 4; ++m) {
      const int g0 = (c << 3) + (lg << 1);
      const f32x4 fa = *reinterpret_cast<const f32x4*>(abase + m * 4096 + (((g0    ) ^ l15) << 4));
      const f32x4 fb = *reinterpret_cast<const f32x4*>(abase + m * 4096 + (((g0 + 1) ^ l15) << 4));
      af[m].b[0]=(__bf16)fa[0]; af[m].b[1]=(__bf16)fa[1];
      af[m].b[2]=(__bf16)fa[2]; af[m].b[3]=(__bf16)fa[3];
      af[m].b[4]=(__bf16)fb[0]; af[m].b[5]=(__bf16)fb[1];
      af[m].b[6]=(__bf16)fb[2]; af[m].b[7]=(__bf16)fb[3];
    }
    __builtin_amdgcn_s_setprio(1);
#pragma unroll
    for (int m = 0; m < 4; ++m)
#pragma unroll
      for (int n = 0; n < 4; ++n)
        acc[m][n] = __builtin_amdgcn_mfma_f32_16x16x32_bf16(
            af[m].b, bfr[c][n].b, acc[m][n], 0, 0, 0);
    __builtin_amdgcn_s_setprio(0);
  }
}

// ---- boundary-tile slow path: per-lane global A gather, masked store ----
template<int DUMMY>
__device__ void redoRun(const float* __restrict__ inp, int t0, int rb, int re,
                        const BF8 (&B)[4][2][4], float* __restrict__ out,
                        int wv, int l15, int lg) {
  f32x4 acc[4][4];
  const f32x4 zero = {0.f, 0.f, 0.f, 0.f};
#pragma unroll
  for (int m = 0; m < 4; ++m)
#pragma unroll
    for (int n = 0; n < 4; ++n) acc[m][n] = zero;
#pragma unroll
  for (int s = 0; s < 4; ++s)
#pragma unroll
    for (int c = 0; c < 2; ++c) {
      BF8 af[4];
#pragma unroll
      for (int m = 0; m < 4; ++m) {
        const float* p = inp + (size_t)(t0 + m * 16 + l15) * KIN + (2 * s + c) * 32 + lg * 8;
        const float4 x = *reinterpret_cast<const float4*>(p);
        const float4 y = *reinterpret_cast<const float4*>(p + 4);
        af[m].u[0]=f2bf(x.x); af[m].u[1]=f2bf(x.y); af[m].u[2]=f2bf(x.z); af[m].u[3]=f2bf(x.w);
        af[m].u[4]=f2bf(y.x); af[m].u[5]=f2bf(y.y); af[m].u[6]=f2bf(y.z); af[m].u[7]=f2bf(y.w);
      }
#pragma unroll
      for (int m = 0; m < 4; ++m)
#pragma unroll
        for (int n = 0; n < 4; ++n)
          acc[m][n] = __builtin_amdgcn_mfma_f32_16x16x32_bf16(
              af[m].b, B[s][c][n].b, acc[m][n], 0, 0, 0);
    }
#pragma unroll
  for (int m = 0; m < 4; ++m) {
    const int rbase = t0 + (m << 4) + (lg << 2);
#pragma unroll
    for (int n = 0; n < 4; ++n) {
      float* op = out + (size_t)rbase * NOUT + (wv << 6) + (n << 4) + l15;
#pragma unroll
      for (int j = 0; j < 4; ++j) {
        const int rg = rbase + j;
        if (rg >= rb && rg < re) op[(size_t)j * NOUT] = acc[m][n][j];
      }
    }
  }
}

// ---- persistent grouped GEMM: 16 tiles/block, B-resident per expert ----
template<bool WSBF>
__global__ __launch_bounds__(256, 2)
void moe_gemm_kernel(const float* __restrict__ inp,
                     const float* w32,
                     const u16* __restrict__ wpk,
                     const int* __restrict__ counts,
                     float* __restrict__ out)
{
  __shared__ float sA[4 * 64 * 64];   // 64 KB: 4 bufs x [64 rows][64 k] fp32

  const int tid  = threadIdx.x;
  const int lane = tid & 63;
  const int wv   = tid >> 6;
  const int l15  = lane & 15;
  const int lg   = lane >> 4;

  // per-wave cumsum of counts via shuffle scan (int32/int64 probe).
  // lane i holds INCLUSIVE cumsum incl[i]; expert e covers [incl[e-1], incl[e]).
  const long long* c64 = reinterpret_cast<const long long*>(counts);
  const long long p0 = c64[0];
  const bool is64 = (p0 >= 0 && p0 < (1ll << 31));
  int c = 0;
  if (lane < 32) c = is64 ? (int)c64[lane] : counts[lane];
#pragma unroll
  for (int d = 1; d < 32; d <<= 1) {
    const int o = __shfl_up(c, d, 64);
    if (lane >= d) c += o;
  }
  const int cum = (lane < 32) ? c : 0x7fffffff;
  auto cumAt    = [&](int i) { return __shfl(cum, i, 64); };       // incl[i]
  auto expertOf = [&](int x) { return (int)__popcll(__ballot(cum <= x)); };

  const int blk0 = blockIdx.x * (BM * TPB);

  // A stage source pointers: instr i covers rows wv*16+i*4..+4 of a tile;
  // physical 16B unit u'=lane&15 <- logical unit g = u' ^ (row&15).
  const float* gp[4];
#pragma unroll
  for (int i = 0; i < 4; ++i) {
    const int r = (wv << 4) + (i << 2) + (lane >> 4);
    const int g = (lane & 15) ^ (r & 15);
    gp[i] = inp + (size_t)(blk0 + r) * KIN + g * 4;
  }
  char* const sAc   = reinterpret_cast<char*>(sA);
  char* const lbase = sAc + wv * 4096;     // + buf*16384 + i*1024 (wave-uniform)

  auto STAGE = [&](int gs) {               // gs = global K-step 0..63
    const size_t off = ((size_t)(gs >> 2) << 14) + (size_t)((gs & 3) << 6);
    char* lb = lbase + ((gs & 3) << 14);
#pragma unroll
    for (int i = 0; i < 4; ++i) GLDS(gp[i] + off, lb + i * 1024);
  };

  BF8 B[4][2][4];
  int cur_e = -1;
  unsigned redo = 0;

  STAGE(0); STAGE(1);

  for (int t = 0; t < TPB; ++t) {
    const int t0 = blk0 + (t << 6);
    const int e  = expertOf(t0);
    const int re = min(t0 + 64, cumAt(e));   // expert e's run ends at incl[e]
    const bool echg = (e != cur_e);
    if (echg) { loadBexp<WSBF>(wpk, w32, e, wv, l15, lg, lane, B); cur_e = e; }
    if (re < t0 + 64) redo |= (1u << t);

    f32x4 acc[4][4];
    const f32x4 zero = {0.f, 0.f, 0.f, 0.f};
#pragma unroll
    for (int m = 0; m < 4; ++m)
#pragma unroll
      for (int n = 0; n < 4; ++n) acc[m][n] = zero;

    const bool lastT = (t == TPB - 1);
#pragma unroll
    for (int s = 0; s < 4; ++s) {
      const int gs = (t << 2) + s;
      if (s < 2 || !lastT) STAGE(gs + 2);
      if (s == 0)      { if (echg) VMW("4"); else VMW("8"); }
      else if (s == 2) { if (lastT) VMW("4"); else VMW("8"); }
      else if (s == 3) { if (lastT) VMW("0"); else VMW("8"); }
      else             VMW("8");
      BAR();
      computeStep(sAc, s, l15, lg, B[s], acc);   // buf == s (t*4 ≡ 0 mod 4)
    }

    // ---- store (C/D map: col=l15, row=lg*4+j) ----
    if (re == t0 + 64) {
#pragma unroll
      for (int m = 0; m < 4; ++m) {
        const int rbase = t0 + (m << 4) + (lg << 2);
#pragma unroll
        for (int n = 0; n < 4; ++n) {
          float* op = out + (size_t)rbase * NOUT + (wv << 6) + (n << 4) + l15;
#pragma unroll
          for (int j = 0; j < 4; ++j) op[(size_t)j * NOUT] = acc[m][n][j];
        }
      }
    } else {
#pragma unroll
      for (int m = 0; m < 4; ++m) {
        const int rbase = t0 + (m << 4) + (lg << 2);
#pragma unroll
        for (int n = 0; n < 4; ++n) {
          float* op = out + (size_t)rbase * NOUT + (wv << 6) + (n << 4) + l15;
#pragma unroll
          for (int j = 0; j < 4; ++j)
            if (rbase + j < re) op[(size_t)j * NOUT] = acc[m][n][j];
        }
      }
    }
  }

  // ---- boundary-tile remainder runs (rare: <=31 tiles chip-wide) ----
  while (redo) {
    const int t = __builtin_ctz(redo); redo &= redo - 1;
    const int t0 = blk0 + (t << 6), t1 = t0 + 64;
    int e  = expertOf(t0);
    int rb = min(t1, cumAt(e));          // end of expert e's run (already stored)
    while (rb < t1) {
      ++e;
      const int re2 = min(t1, cumAt(e)); // end of expert e's run
      if (re2 > rb) {
        loadBexp<WSBF>(wpk, w32, e, wv, l15, lg, lane, B);
        redoRun<0>(inp, t0, rb, re2, B, out, wv, l15, lg);
      }
      rb = re2 > rb ? re2 : rb;
    }
  }
}

extern "C" void kernel_launch(void* const* d_in, const int* in_sizes, int n_in,
                              void* d_out, int out_size, void* d_ws, size_t ws_size,
                              hipStream_t stream) {
  const float* inp    = (const float*)d_in[0];
  const float* w      = (const float*)d_in[1];
  const int*   counts = (const int*)d_in[2];
  float*       out    = (float*)d_out;

  const size_t wbytes = (size_t)NEXPERT * NOUT * KIN * 2;  // 4 MB packed bf16 W
  const bool usews = (ws_size >= wbytes);

  if (usews) {
    u16* wpk = (u16*)d_ws;
    pack_w_kernel<<<1024, 256, 0, stream>>>(w, wpk);
    moe_gemm_kernel<true><<<NTOK / (BM * TPB), 256, 0, stream>>>(inp, w, wpk, counts, out);
  } else {
    moe_gemm_kernel<false><<<NTOK / (BM * TPB), 256, 0, stream>>>(inp, w, nullptr, counts, out);
  }
}